// Round 1
// baseline (85.255 us; speedup 1.0000x reference)
//
#include <hip/hip_runtime.h>
#include <hip/hip_bf16.h>

// Problem constants (KANLayer): B=8192, I=256, O=256, NUM_BASIS=7, ORDER=3
#define B_SZ 8192
#define I_SZ 256
#define O_SZ 256
#define KDIM 2048  // I_SZ * 8  (7 basis + 1 silu per input feature)

typedef __bf16 bf16x8 __attribute__((ext_vector_type(8)));
typedef float f32x4 __attribute__((ext_vector_type(4)));

// ---- monotone uint <-> float for order-independent atomic min/max ----
__device__ __forceinline__ unsigned fkey(float f) {
  unsigned u = __float_as_uint(f);
  return (u & 0x80000000u) ? ~u : (u | 0x80000000u);
}
__device__ __forceinline__ float funkey(unsigned k) {
  unsigned u = (k & 0x80000000u) ? (k ^ 0x80000000u) : ~k;
  return __uint_as_float(u);
}

// Kernel 1: per-column min/max over the batch (coalesced row reads, atomics)
__global__ void minmax_partial(const float* __restrict__ x,
                               unsigned* __restrict__ smin,
                               unsigned* __restrict__ smax) {
  const int col = threadIdx.x;          // 256 threads = one per column
  const int rows = B_SZ / gridDim.x;    // 64 blocks -> 128 rows each
  const int r0 = blockIdx.x * rows;
  float mn = 1e30f, mx = -1e30f;
  for (int r = 0; r < rows; ++r) {
    float v = x[(size_t)(r0 + r) * I_SZ + col];
    mn = fminf(mn, v);
    mx = fmaxf(mx, v);
  }
  atomicMin(&smin[col], fkey(mn));
  atomicMax(&smax[col], fkey(mx));
}

// Kernel 2: pack weights -> Wp[o, i*8+m] bf16, pre-swizzled (col-block ^= o&7)
__global__ void pack_W(const float* __restrict__ bw,
                       const float* __restrict__ sw,
                       const float* __restrict__ coeff,
                       __hip_bfloat16* __restrict__ W) {
  const int idx = blockIdx.x * blockDim.x + threadIdx.x;  // 0..O*I-1
  const int i = idx & (I_SZ - 1);
  const int o = idx >> 8;
  const float s = sw[idx];
  union { __hip_bfloat16 h[8]; float4 f4; } u;
#pragma unroll
  for (int m = 0; m < 7; ++m)
    u.h[m] = __float2bfloat16(coeff[(size_t)idx * 7 + m] * s);
  u.h[7] = __float2bfloat16(bw[idx]);
  const size_t off = (size_t)o * KDIM + (size_t)((i ^ (o & 7)) << 3);
  *reinterpret_cast<float4*>(&W[off]) = u.f4;
}

// Kernel 3: normalize + truncated de Boor cubic basis + silu -> A bf16,
// pre-swizzled (col-block ^= b&7) so GEMM's linear global_load_lds + XOR'd
// ds_read is bank-conflict-free.
__global__ void build_A(const float* __restrict__ x,
                        const unsigned* __restrict__ smin,
                        const unsigned* __restrict__ smax,
                        __hip_bfloat16* __restrict__ A) {
  const int idx = blockIdx.x * blockDim.x + threadIdx.x;  // 0..B*I-1
  const int i = idx & (I_SZ - 1);
  const int b = idx >> 8;

  const float mn = funkey(smin[i]);
  const float mx = funkey(smax[i]);
  const float width = fmaxf(mx - mn, 0.01f);
  const float centre = 0.5f * (mx + mn);
  float xn = (x[idx] - centre) / (0.5f * width);
  xn = fminf(fmaxf(xn, -2.0f), 2.0f);

  // knots = linspace(-1,1,11); replicate reference's TRUNCATED recursion
  constexpr float KT[11] = {-1.0f, -0.8f, -0.6f, -0.4f, -0.2f, 0.0f,
                            0.2f,  0.4f,  0.6f,  0.8f,  1.0f};
  float bas[7];
#pragma unroll
  for (int j = 0; j < 7; ++j)
    bas[j] = (xn >= KT[j] && xn < KT[j + 1]) ? 1.0f : 0.0f;
  if (xn == KT[7]) bas[6] = 1.0f;
#pragma unroll
  for (int k = 1; k <= 3; ++k) {
#pragma unroll
    for (int j = 0; j < 7; ++j) {
      const float r1 = 1.0f / (KT[j + k] - KT[j]);           // const-folded
      const float r2 = 1.0f / (KT[j + k + 1] - KT[j + 1]);   // const-folded
      const float bn = (j < 6) ? bas[j + 1] : 0.0f;
      bas[j] = (xn - KT[j]) * r1 * bas[j] + (KT[j + k + 1] - xn) * r2 * bn;
    }
  }
  const float silu = xn / (1.0f + __expf(-xn));

  union { __hip_bfloat16 h[8]; float4 f4; } u;
#pragma unroll
  for (int m = 0; m < 7; ++m) u.h[m] = __float2bfloat16(bas[m]);
  u.h[7] = __float2bfloat16(silu);
  const size_t off = (size_t)b * KDIM + (size_t)((i ^ (b & 7)) << 3);
  *reinterpret_cast<float4*>(&A[off]) = u.f4;
}

// ---- async global->LDS 16B copy ----
__device__ __forceinline__ void async16(const __hip_bfloat16* g, __hip_bfloat16* l) {
  __builtin_amdgcn_global_load_lds(
      (const __attribute__((address_space(1))) void*)g,
      (__attribute__((address_space(3))) void*)l, 16, 0, 0);
}

// Kernel 4: out[M=8192, N=256] = A[M,K=2048] @ W[N,K]^T + bias
// BM=BN=BK=64, 256 threads (4 waves, 2x2), 2-phase double-buffered LDS,
// global_load_lds width-16 staging, XOR-swizzled LDS reads (source-side swz).
__global__ __launch_bounds__(256, 2) void gemm_kan(
    const __hip_bfloat16* __restrict__ A, const __hip_bfloat16* __restrict__ W,
    const float* __restrict__ bias, float* __restrict__ out) {
  __shared__ __align__(16) __hip_bfloat16 Alds[2][64 * 64];
  __shared__ __align__(16) __hip_bfloat16 Blds[2][64 * 64];

  const int t = threadIdx.x;
  const int lane = t & 63;
  const int wave = t >> 6;
  const int wm = wave >> 1, wn = wave & 1;   // wave grid 2x2 over 64x64 tile
  const int fr = lane & 15, fk = lane >> 4;  // fragment row / k-segment

  // XCD-aware bijective swizzle (grid=512, %8==0)
  const int bid = blockIdx.x;
  const int swz = (bid & 7) * ((int)gridDim.x >> 3) + (bid >> 3);
  const int bm = swz >> 2, bn = swz & 3;  // N/BN = 4
  const int rowBase = bm * 64, colBase = bn * 64;

  // staging: thread t covers tile-row t>>3 (issue0) / +32 (issue1), seg t&7
  const int srow = t >> 3, sseg = t & 7;
  const __hip_bfloat16* ga = A + (size_t)(rowBase + srow) * KDIM + sseg * 8;
  const __hip_bfloat16* gb = W + (size_t)(colBase + srow) * KDIM + sseg * 8;

  f32x4 acc[2][2] = {{{0.f, 0.f, 0.f, 0.f}, {0.f, 0.f, 0.f, 0.f}},
                     {{0.f, 0.f, 0.f, 0.f}, {0.f, 0.f, 0.f, 0.f}}};

  auto stage = [&](int buf, int kt) {
    const size_t k0 = (size_t)kt * 64;
    async16(ga + k0, &Alds[buf][t * 8]);
    async16(ga + k0 + (size_t)32 * KDIM, &Alds[buf][2048 + t * 8]);
    async16(gb + k0, &Blds[buf][t * 8]);
    async16(gb + k0 + (size_t)32 * KDIM, &Blds[buf][2048 + t * 8]);
  };

  auto compute = [&](int buf) {
    bf16x8 af[2][2], bg[2][2];
#pragma unroll
    for (int m = 0; m < 2; ++m)
#pragma unroll
      for (int kk = 0; kk < 2; ++kk) {
        const int row = wm * 32 + m * 16 + fr;
        const int eo = row * 64 + ((((kk << 2) | fk) ^ (row & 7)) << 3);
        af[m][kk] = *reinterpret_cast<const bf16x8*>(&Alds[buf][eo]);
      }
#pragma unroll
    for (int n = 0; n < 2; ++n)
#pragma unroll
      for (int kk = 0; kk < 2; ++kk) {
        const int row = wn * 32 + n * 16 + fr;
        const int eo = row * 64 + ((((kk << 2) | fk) ^ (row & 7)) << 3);
        bg[n][kk] = *reinterpret_cast<const bf16x8*>(&Blds[buf][eo]);
      }
#pragma unroll
    for (int kk = 0; kk < 2; ++kk)
#pragma unroll
      for (int m = 0; m < 2; ++m)
#pragma unroll
        for (int n = 0; n < 2; ++n)
          acc[m][n] = __builtin_amdgcn_mfma_f32_16x16x32_bf16(
              af[m][kk], bg[n][kk], acc[m][n], 0, 0, 0);
  };

  stage(0, 0);
  __syncthreads();  // drains vmcnt(0): staged data visible
  int cur = 0;
  const int NT = KDIM / 64;  // 32
  for (int kt = 0; kt < NT - 1; ++kt) {
    stage(cur ^ 1, kt + 1);  // prefetch next tile (in flight across compute)
    compute(cur);
    __syncthreads();         // drain prefetch + all waves done reading
    cur ^= 1;
  }
  compute(cur);

  // epilogue: C/D layout col=lane&15, row=(lane>>4)*4+reg  [m89/m91]
#pragma unroll
  for (int m = 0; m < 2; ++m)
#pragma unroll
    for (int n = 0; n < 2; ++n) {
      const int col = colBase + wn * 32 + n * 16 + fr;
      const float bc = bias[col];
#pragma unroll
      for (int r = 0; r < 4; ++r) {
        const int row = rowBase + wm * 32 + m * 16 + fk * 4 + r;
        out[(size_t)row * O_SZ + col] = acc[m][n][r] + bc;
      }
    }
}

extern "C" void kernel_launch(void* const* d_in, const int* in_sizes, int n_in,
                              void* d_out, int out_size, void* d_ws, size_t ws_size,
                              hipStream_t stream) {
  const float* x     = (const float*)d_in[0];
  const float* bw    = (const float*)d_in[1];
  const float* sw    = (const float*)d_in[2];
  const float* coeff = (const float*)d_in[3];
  const float* bias  = (const float*)d_in[4];
  float* out = (float*)d_out;

  char* ws = (char*)d_ws;
  __hip_bfloat16* Abuf = (__hip_bfloat16*)ws;                               // 32 MiB
  __hip_bfloat16* Wbuf = (__hip_bfloat16*)(ws + (size_t)B_SZ * KDIM * 2);   // 1 MiB
  unsigned* smin = (unsigned*)(ws + (size_t)B_SZ * KDIM * 2 + (size_t)O_SZ * KDIM * 2);
  unsigned* smax = smin + I_SZ;

  hipMemsetAsync(smin, 0xFF, I_SZ * sizeof(unsigned), stream);  // key(min) identity
  hipMemsetAsync(smax, 0x00, I_SZ * sizeof(unsigned), stream);  // key(max) identity

  minmax_partial<<<64, 256, 0, stream>>>(x, smin, smax);
  pack_W<<<(O_SZ * I_SZ) / 256, 256, 0, stream>>>(bw, sw, coeff, Wbuf);
  build_A<<<(B_SZ * I_SZ) / 256, 256, 0, stream>>>(x, smin, smax, Abuf);
  gemm_kan<<<(B_SZ / 64) * (O_SZ / 64), 256, 0, stream>>>(Abuf, Wbuf, bias, out);
}

// Round 2
// 65.286 us; speedup vs baseline: 1.3059x; 1.3059x over previous
//
#include <hip/hip_runtime.h>
#include <hip/hip_bf16.h>

// Problem constants (KANLayer): B=8192, I=256, O=256, NUM_BASIS=7, ORDER=3
#define B_SZ 8192
#define I_SZ 256
#define O_SZ 256
#define KDIM 2048  // I_SZ * 8  (7 basis + 1 silu per input feature)

typedef __bf16 bf16x8 __attribute__((ext_vector_type(8)));
typedef float f32x4 __attribute__((ext_vector_type(4)));

// ---- monotone uint <-> float for order-independent atomic min/max ----
__device__ __forceinline__ unsigned fkey(float f) {
  unsigned u = __float_as_uint(f);
  return (u & 0x80000000u) ? ~u : (u | 0x80000000u);
}
__device__ __forceinline__ float funkey(unsigned k) {
  unsigned u = (k & 0x80000000u) ? (k ^ 0x80000000u) : ~k;
  return __uint_as_float(u);
}

// Kernel 1: per-column min/max over the batch.
// 128 blocks x 256 threads; block handles 64 rows; thread handles 4 columns
// via float4 over 16 unrolled independent loads (latency-hiding ILP), then
// LDS reduce over the 4 row-subgroups, then 64 threads do the atomics.
__global__ __launch_bounds__(256) void minmax_partial(
    const float* __restrict__ x, unsigned* __restrict__ smin,
    unsigned* __restrict__ smax) {
  const int cg = threadIdx.x & 63;  // column group (4 cols via float4)
  const int rs = threadIdx.x >> 6;  // row subgroup 0..3
  const int r0 = blockIdx.x * 64;
  const float* p = x + (size_t)(r0 + rs) * I_SZ + cg * 4;
  float4 mn = {1e30f, 1e30f, 1e30f, 1e30f};
  float4 mx = {-1e30f, -1e30f, -1e30f, -1e30f};
#pragma unroll
  for (int k = 0; k < 16; ++k) {
    const float4 v = *reinterpret_cast<const float4*>(p + (size_t)k * 4 * I_SZ);
    mn.x = fminf(mn.x, v.x); mn.y = fminf(mn.y, v.y);
    mn.z = fminf(mn.z, v.z); mn.w = fminf(mn.w, v.w);
    mx.x = fmaxf(mx.x, v.x); mx.y = fmaxf(mx.y, v.y);
    mx.z = fmaxf(mx.z, v.z); mx.w = fmaxf(mx.w, v.w);
  }
  __shared__ float rmn[4][I_SZ], rmx[4][I_SZ];
  *reinterpret_cast<float4*>(&rmn[rs][cg * 4]) = mn;
  *reinterpret_cast<float4*>(&rmx[rs][cg * 4]) = mx;
  __syncthreads();
  if (threadIdx.x < 64) {
#pragma unroll
    for (int c = 0; c < 4; ++c) {
      const int col = threadIdx.x * 4 + c;
      const float a = fminf(fminf(rmn[0][col], rmn[1][col]),
                            fminf(rmn[2][col], rmn[3][col]));
      const float b = fmaxf(fmaxf(rmx[0][col], rmx[1][col]),
                            fmaxf(rmx[2][col], rmx[3][col]));
      atomicMin(&smin[col], fkey(a));
      atomicMax(&smax[col], fkey(b));
    }
  }
}

// Kernel 2: pack weights -> Wp[o, i*8+m] bf16, pre-swizzled (col-block ^= o&7)
__global__ void pack_W(const float* __restrict__ bw,
                       const float* __restrict__ sw,
                       const float* __restrict__ coeff,
                       __hip_bfloat16* __restrict__ W) {
  const int idx = blockIdx.x * blockDim.x + threadIdx.x;  // 0..O*I-1
  const int i = idx & (I_SZ - 1);
  const int o = idx >> 8;
  const float s = sw[idx];
  union { __hip_bfloat16 h[8]; float4 f4; } u;
#pragma unroll
  for (int m = 0; m < 7; ++m)
    u.h[m] = __float2bfloat16(coeff[(size_t)idx * 7 + m] * s);
  u.h[7] = __float2bfloat16(bw[idx]);
  const size_t off = (size_t)o * KDIM + (size_t)((i ^ (o & 7)) << 3);
  *reinterpret_cast<float4*>(&W[off]) = u.f4;
}

// Kernel 3: normalize + truncated de Boor cubic basis + silu -> A bf16,
// pre-swizzled (col-block ^= b&7) so GEMM's linear global_load_lds + XOR'd
// ds_read is bank-conflict-free.
__global__ void build_A(const float* __restrict__ x,
                        const unsigned* __restrict__ smin,
                        const unsigned* __restrict__ smax,
                        __hip_bfloat16* __restrict__ A) {
  const int idx = blockIdx.x * blockDim.x + threadIdx.x;  // 0..B*I-1
  const int i = idx & (I_SZ - 1);
  const int b = idx >> 8;

  const float mn = funkey(smin[i]);
  const float mx = funkey(smax[i]);
  const float width = fmaxf(mx - mn, 0.01f);
  const float centre = 0.5f * (mx + mn);
  float xn = (x[idx] - centre) / (0.5f * width);
  xn = fminf(fmaxf(xn, -2.0f), 2.0f);

  // knots = linspace(-1,1,11); replicate reference's TRUNCATED recursion
  constexpr float KT[11] = {-1.0f, -0.8f, -0.6f, -0.4f, -0.2f, 0.0f,
                            0.2f,  0.4f,  0.6f,  0.8f,  1.0f};
  float bas[7];
#pragma unroll
  for (int j = 0; j < 7; ++j)
    bas[j] = (xn >= KT[j] && xn < KT[j + 1]) ? 1.0f : 0.0f;
  if (xn == KT[7]) bas[6] = 1.0f;
#pragma unroll
  for (int k = 1; k <= 3; ++k) {
#pragma unroll
    for (int j = 0; j < 7; ++j) {
      const float r1 = 1.0f / (KT[j + k] - KT[j]);           // const-folded
      const float r2 = 1.0f / (KT[j + k + 1] - KT[j + 1]);   // const-folded
      const float bn = (j < 6) ? bas[j + 1] : 0.0f;
      bas[j] = (xn - KT[j]) * r1 * bas[j] + (KT[j + k + 1] - xn) * r2 * bn;
    }
  }
  const float silu = xn / (1.0f + __expf(-xn));

  union { __hip_bfloat16 h[8]; float4 f4; } u;
#pragma unroll
  for (int m = 0; m < 7; ++m) u.h[m] = __float2bfloat16(bas[m]);
  u.h[7] = __float2bfloat16(silu);
  const size_t off = (size_t)b * KDIM + (size_t)((i ^ (b & 7)) << 3);
  *reinterpret_cast<float4*>(&A[off]) = u.f4;
}

// ---- async global->LDS 16B copy ----
__device__ __forceinline__ void async16(const __hip_bfloat16* g, __hip_bfloat16* l) {
  __builtin_amdgcn_global_load_lds(
      (const __attribute__((address_space(1))) void*)g,
      (__attribute__((address_space(3))) void*)l, 16, 0, 0);
}

// Kernel 4: out[M=8192, N=256] = A[M,K=2048] @ W[N,K]^T + bias
// BM=BN=BK=64, 256 threads (4 waves, 2x2), 2-phase double-buffered LDS,
// global_load_lds width-16 staging, XOR-swizzled LDS reads (source-side swz).
__global__ __launch_bounds__(256, 2) void gemm_kan(
    const __hip_bfloat16* __restrict__ A, const __hip_bfloat16* __restrict__ W,
    const float* __restrict__ bias, float* __restrict__ out) {
  __shared__ __align__(16) __hip_bfloat16 Alds[2][64 * 64];
  __shared__ __align__(16) __hip_bfloat16 Blds[2][64 * 64];

  const int t = threadIdx.x;
  const int lane = t & 63;
  const int wave = t >> 6;
  const int wm = wave >> 1, wn = wave & 1;   // wave grid 2x2 over 64x64 tile
  const int fr = lane & 15, fk = lane >> 4;  // fragment row / k-segment

  // XCD-aware bijective swizzle (grid=512, %8==0)
  const int bid = blockIdx.x;
  const int swz = (bid & 7) * ((int)gridDim.x >> 3) + (bid >> 3);
  const int bm = swz >> 2, bn = swz & 3;  // N/BN = 4
  const int rowBase = bm * 64, colBase = bn * 64;

  // staging: thread t covers tile-row t>>3 (issue0) / +32 (issue1), seg t&7
  const int srow = t >> 3, sseg = t & 7;
  const __hip_bfloat16* ga = A + (size_t)(rowBase + srow) * KDIM + sseg * 8;
  const __hip_bfloat16* gb = W + (size_t)(colBase + srow) * KDIM + sseg * 8;

  f32x4 acc[2][2] = {{{0.f, 0.f, 0.f, 0.f}, {0.f, 0.f, 0.f, 0.f}},
                     {{0.f, 0.f, 0.f, 0.f}, {0.f, 0.f, 0.f, 0.f}}};

  auto stage = [&](int buf, int kt) {
    const size_t k0 = (size_t)kt * 64;
    async16(ga + k0, &Alds[buf][t * 8]);
    async16(ga + k0 + (size_t)32 * KDIM, &Alds[buf][2048 + t * 8]);
    async16(gb + k0, &Blds[buf][t * 8]);
    async16(gb + k0 + (size_t)32 * KDIM, &Blds[buf][2048 + t * 8]);
  };

  auto compute = [&](int buf) {
    bf16x8 af[2][2], bg[2][2];
#pragma unroll
    for (int m = 0; m < 2; ++m)
#pragma unroll
      for (int kk = 0; kk < 2; ++kk) {
        const int row = wm * 32 + m * 16 + fr;
        const int eo = row * 64 + ((((kk << 2) | fk) ^ (row & 7)) << 3);
        af[m][kk] = *reinterpret_cast<const bf16x8*>(&Alds[buf][eo]);
      }
#pragma unroll
    for (int n = 0; n < 2; ++n)
#pragma unroll
      for (int kk = 0; kk < 2; ++kk) {
        const int row = wn * 32 + n * 16 + fr;
        const int eo = row * 64 + ((((kk << 2) | fk) ^ (row & 7)) << 3);
        bg[n][kk] = *reinterpret_cast<const bf16x8*>(&Blds[buf][eo]);
      }
#pragma unroll
    for (int kk = 0; kk < 2; ++kk)
#pragma unroll
      for (int m = 0; m < 2; ++m)
#pragma unroll
        for (int n = 0; n < 2; ++n)
          acc[m][n] = __builtin_amdgcn_mfma_f32_16x16x32_bf16(
              af[m][kk], bg[n][kk], acc[m][n], 0, 0, 0);
  };

  stage(0, 0);
  __syncthreads();  // drains vmcnt(0): staged data visible
  int cur = 0;
  const int NT = KDIM / 64;  // 32
  for (int kt = 0; kt < NT - 1; ++kt) {
    stage(cur ^ 1, kt + 1);  // prefetch next tile (in flight across compute)
    compute(cur);
    __syncthreads();         // drain prefetch + all waves done reading
    cur ^= 1;
  }
  compute(cur);

  // epilogue: C/D layout col=lane&15, row=(lane>>4)*4+reg  [m89/m91]
#pragma unroll
  for (int m = 0; m < 2; ++m)
#pragma unroll
    for (int n = 0; n < 2; ++n) {
      const int col = colBase + wn * 32 + n * 16 + fr;
      const float bc = bias[col];
#pragma unroll
      for (int r = 0; r < 4; ++r) {
        const int row = rowBase + wm * 32 + m * 16 + fk * 4 + r;
        out[(size_t)row * O_SZ + col] = acc[m][n][r] + bc;
      }
    }
}

extern "C" void kernel_launch(void* const* d_in, const int* in_sizes, int n_in,
                              void* d_out, int out_size, void* d_ws, size_t ws_size,
                              hipStream_t stream) {
  const float* x     = (const float*)d_in[0];
  const float* bw    = (const float*)d_in[1];
  const float* sw    = (const float*)d_in[2];
  const float* coeff = (const float*)d_in[3];
  const float* bias  = (const float*)d_in[4];
  float* out = (float*)d_out;

  char* ws = (char*)d_ws;
  __hip_bfloat16* Abuf = (__hip_bfloat16*)ws;                               // 32 MiB
  __hip_bfloat16* Wbuf = (__hip_bfloat16*)(ws + (size_t)B_SZ * KDIM * 2);   // 1 MiB
  unsigned* smin = (unsigned*)(ws + (size_t)B_SZ * KDIM * 2 + (size_t)O_SZ * KDIM * 2);
  unsigned* smax = smin + I_SZ;

  hipMemsetAsync(smin, 0xFF, I_SZ * sizeof(unsigned), stream);  // key(min) identity
  hipMemsetAsync(smax, 0x00, I_SZ * sizeof(unsigned), stream);  // key(max) identity

  minmax_partial<<<128, 256, 0, stream>>>(x, smin, smax);
  pack_W<<<(O_SZ * I_SZ) / 256, 256, 0, stream>>>(bw, sw, coeff, Wbuf);
  build_A<<<(B_SZ * I_SZ) / 256, 256, 0, stream>>>(x, smin, smax, Abuf);
  gemm_kan<<<(B_SZ / 64) * (O_SZ / 64), 256, 0, stream>>>(Abuf, Wbuf, bias, out);
}

// Round 3
// 52.720 us; speedup vs baseline: 1.6171x; 1.2384x over previous
//
#include <hip/hip_runtime.h>
#include <hip/hip_bf16.h>

// Problem constants (KANLayer): B=8192, I=256, O=256, NUM_BASIS=7, ORDER=3
#define B_SZ 8192
#define I_SZ 256
#define O_SZ 256
#define KDIM 2048  // I_SZ * 8  (7 basis + 1 silu per input feature)
#define BM 64      // rows per block
#define BN 128     // output cols per block
#define BKT 64     // K per tile = 8 features
#define NT 32      // KDIM / BKT

typedef __bf16 bf16x8 __attribute__((ext_vector_type(8)));
typedef float f32x4 __attribute__((ext_vector_type(4)));

// Kernel 1: per-column min/max partials. 128 blocks x 256 threads; block
// handles 64 rows via float4 loads (ILP), LDS-reduce over 4 row-subgroups,
// plain stores of one partial row per block (no atomics, no memset needed).
__global__ __launch_bounds__(256) void minmax_partial(
    const float* __restrict__ x, float* __restrict__ pmin,
    float* __restrict__ pmax) {
  const int cg = threadIdx.x & 63;  // column group (4 cols via float4)
  const int rs = threadIdx.x >> 6;  // row subgroup 0..3
  const int r0 = blockIdx.x * 64;
  const float* p = x + (size_t)(r0 + rs) * I_SZ + cg * 4;
  float4 mn = {1e30f, 1e30f, 1e30f, 1e30f};
  float4 mx = {-1e30f, -1e30f, -1e30f, -1e30f};
#pragma unroll
  for (int k = 0; k < 16; ++k) {
    const float4 v = *reinterpret_cast<const float4*>(p + (size_t)k * 4 * I_SZ);
    mn.x = fminf(mn.x, v.x); mn.y = fminf(mn.y, v.y);
    mn.z = fminf(mn.z, v.z); mn.w = fminf(mn.w, v.w);
    mx.x = fmaxf(mx.x, v.x); mx.y = fmaxf(mx.y, v.y);
    mx.z = fmaxf(mx.z, v.z); mx.w = fmaxf(mx.w, v.w);
  }
  __shared__ float rmn[4][I_SZ], rmx[4][I_SZ];
  *reinterpret_cast<float4*>(&rmn[rs][cg * 4]) = mn;
  *reinterpret_cast<float4*>(&rmx[rs][cg * 4]) = mx;
  __syncthreads();
  if (threadIdx.x < 64) {
    float4 a, b;
    const int c0 = threadIdx.x * 4;
    a.x = fminf(fminf(rmn[0][c0+0], rmn[1][c0+0]), fminf(rmn[2][c0+0], rmn[3][c0+0]));
    a.y = fminf(fminf(rmn[0][c0+1], rmn[1][c0+1]), fminf(rmn[2][c0+1], rmn[3][c0+1]));
    a.z = fminf(fminf(rmn[0][c0+2], rmn[1][c0+2]), fminf(rmn[2][c0+2], rmn[3][c0+2]));
    a.w = fminf(fminf(rmn[0][c0+3], rmn[1][c0+3]), fminf(rmn[2][c0+3], rmn[3][c0+3]));
    b.x = fmaxf(fmaxf(rmx[0][c0+0], rmx[1][c0+0]), fmaxf(rmx[2][c0+0], rmx[3][c0+0]));
    b.y = fmaxf(fmaxf(rmx[0][c0+1], rmx[1][c0+1]), fmaxf(rmx[2][c0+1], rmx[3][c0+1]));
    b.z = fmaxf(fmaxf(rmx[0][c0+2], rmx[1][c0+2]), fmaxf(rmx[2][c0+2], rmx[3][c0+2]));
    b.w = fmaxf(fmaxf(rmx[0][c0+3], rmx[1][c0+3]), fmaxf(rmx[2][c0+3], rmx[3][c0+3]));
    *reinterpret_cast<float4*>(&pmin[blockIdx.x * I_SZ + c0]) = a;
    *reinterpret_cast<float4*>(&pmax[blockIdx.x * I_SZ + c0]) = b;
  }
}

// Kernel 2: pack weights -> Wp[o, i*8+m] bf16, pre-swizzled (unit ^= o&7),
// PLUS (block 0) reduce the min/max partials into per-column centre and
// 1/half-width so the GEMM reads scales directly.
__global__ void pack_W(const float* __restrict__ bw,
                       const float* __restrict__ sw,
                       const float* __restrict__ coeff,
                       __hip_bfloat16* __restrict__ W,
                       const float* __restrict__ pmin,
                       const float* __restrict__ pmax,
                       float* __restrict__ cenrhw) {
  const int idx = blockIdx.x * blockDim.x + threadIdx.x;  // 0..O*I-1
  const int i = idx & (I_SZ - 1);
  const int o = idx >> 8;
  const float s = sw[idx];
  union { __hip_bfloat16 h[8]; float4 f4; } u;
#pragma unroll
  for (int m = 0; m < 7; ++m)
    u.h[m] = __float2bfloat16(coeff[(size_t)idx * 7 + m] * s);
  u.h[7] = __float2bfloat16(bw[idx]);
  const size_t off = (size_t)o * KDIM + (size_t)((i ^ (o & 7)) << 3);
  *reinterpret_cast<float4*>(&W[off]) = u.f4;

  if (blockIdx.x == 0) {
    const int c = threadIdx.x;
    float mn = 1e30f, mx = -1e30f;
#pragma unroll 8
    for (int p = 0; p < 128; ++p) {
      mn = fminf(mn, pmin[p * I_SZ + c]);
      mx = fmaxf(mx, pmax[p * I_SZ + c]);
    }
    const float width = fmaxf(mx - mn, 0.01f);
    cenrhw[2 * c]     = 0.5f * (mx + mn);
    cenrhw[2 * c + 1] = 2.0f / width;   // 1/(0.5*width)
  }
}

// ---- async global->LDS 16B copy ----
__device__ __forceinline__ void async16(const __hip_bfloat16* g, __hip_bfloat16* l) {
  __builtin_amdgcn_global_load_lds(
      (const __attribute__((address_space(1))) void*)g,
      (__attribute__((address_space(3))) void*)l, 16, 0, 0);
}

// Kernel 3: fused basis-build + GEMM.
// out[M=8192, N=256] = A(x)[M, K=2048] @ W[N, K]^T + bias, where A is built
// on the fly per K-tile: 8 bf16 per (row, feature) = 7 truncated-de-Boor
// cubic basis values + silu. Block = 64 rows x 128 cols, 512 threads
// (8 waves, 2m x 4n), double-buffered LDS, B staged via global_load_lds
// from pre-swizzled Wbuf, A ds_written with matching XOR swizzle.
__global__ __launch_bounds__(512, 2) void gemm_fused(
    const float* __restrict__ x, const __hip_bfloat16* __restrict__ W,
    const float* __restrict__ cenrhw, const float* __restrict__ bias,
    float* __restrict__ out) {
  __shared__ __align__(16) __hip_bfloat16 Alds[2][BM * BKT];   // 2 x 8KB
  __shared__ __align__(16) __hip_bfloat16 Blds[2][BN * BKT];   // 2 x 16KB
  __shared__ float2 scl[I_SZ];                                  // 2KB

  const int t = threadIdx.x;
  const int lane = t & 63;
  const int wave = t >> 6;            // 0..7
  const int wm = wave >> 2;           // 0..1 -> m-offset 32*wm
  const int wn = wave & 3;            // 0..3 -> n-offset 32*wn
  const int fr = lane & 15, fk = lane >> 4;

  // XCD-aware bijective swizzle (256 blocks, %8==0); pair (bn=0,1) of the
  // same bm lands adjacent on one XCD -> shared x rows hit L2.
  const int bid = blockIdx.x;
  const int swz = (bid & 7) * 32 + (bid >> 3);
  const int bm = swz >> 1, bn = swz & 1;
  const int r0 = bm * BM;    // batch-row base
  const int c0 = bn * BN;    // output-col base

  // per-column scale factors -> LDS
  if (t < I_SZ) scl[t] = reinterpret_cast<const float2*>(cenrhw)[t];

  // A-build mapping: thread -> (row, feature-within-tile)
  const int arow = t >> 3;   // 0..63
  const int af_  = t & 7;    // 0..7

  // B staging: LDS 16B-unit p = t (rows 0..63) and p = 512+t (rows 64..127)
  const __hip_bfloat16* gb0 = W + (size_t)(c0 + (t >> 3)) * KDIM + (t & 7) * 8;
  const __hip_bfloat16* gb1 = gb0 + (size_t)64 * KDIM;

  f32x4 acc[2][2] = {{{0.f,0.f,0.f,0.f},{0.f,0.f,0.f,0.f}},
                     {{0.f,0.f,0.f,0.f},{0.f,0.f,0.f,0.f}}};

  auto stageB = [&](int buf, int kt) {
    const size_t k0 = (size_t)kt * BKT;
    async16(gb0 + k0, &Blds[buf][t * 8]);
    async16(gb1 + k0, &Blds[buf][4096 + t * 8]);
  };

  auto buildA = [&](int buf, int kt) {
    const int i = kt * 8 + af_;
    const float2 s = scl[i];
    const float xv = x[(size_t)(r0 + arow) * I_SZ + i];
    float xn = (xv - s.x) * s.y;
    xn = fminf(fmaxf(xn, -2.0f), 2.0f);
    // d[j] = xn - KT[j], KT[j] = -1 + 0.2j (uniform knots)
    float d[11];
#pragma unroll
    for (int j = 0; j < 11; ++j) d[j] = xn - (-1.0f + 0.2f * j);
    float bas[7];
#pragma unroll
    for (int j = 0; j < 7; ++j)
      bas[j] = (d[j] >= 0.0f && d[j + 1] < 0.0f) ? 1.0f : 0.0f;
    if (d[7] == 0.0f) bas[6] = 1.0f;  // xe == KNOTS[7] special case
    // truncated de Boor; uniform knots: both denominators = 0.2k
#pragma unroll
    for (int k = 1; k <= 3; ++k) {
      const float rk = (k == 1) ? 5.0f : (k == 2) ? 2.5f : (1.0f / 0.6f);
#pragma unroll
      for (int j = 0; j < 7; ++j) {
        const float bn_ = (j < 6) ? bas[j + 1] : 0.0f;
        bas[j] = (d[j] * bas[j] - d[j + k + 1] * bn_) * rk;
      }
    }
    const float silu = xn / (1.0f + __expf(-xn));
    union { __hip_bfloat16 h[8]; float4 f4; } u;
#pragma unroll
    for (int m = 0; m < 7; ++m) u.h[m] = __float2bfloat16(bas[m]);
    u.h[7] = __float2bfloat16(silu);
    const int unit = af_ ^ (arow & 7);
    *reinterpret_cast<float4*>(&Alds[buf][arow * BKT + unit * 8]) = u.f4;
  };

  auto compute = [&](int buf) {
    bf16x8 af[2][2], bg[2][2];
#pragma unroll
    for (int m = 0; m < 2; ++m)
#pragma unroll
      for (int kk = 0; kk < 2; ++kk) {
        const int row = wm * 32 + m * 16 + fr;
        const int unit = ((kk << 2) | fk) ^ (row & 7);
        af[m][kk] = *reinterpret_cast<const bf16x8*>(&Alds[buf][row * BKT + unit * 8]);
      }
#pragma unroll
    for (int n = 0; n < 2; ++n)
#pragma unroll
      for (int kk = 0; kk < 2; ++kk) {
        const int row = wn * 32 + n * 16 + fr;
        const int unit = ((kk << 2) | fk) ^ (row & 7);
        bg[n][kk] = *reinterpret_cast<const bf16x8*>(&Blds[buf][row * BKT + unit * 8]);
      }
#pragma unroll
    for (int kk = 0; kk < 2; ++kk)
#pragma unroll
      for (int m = 0; m < 2; ++m)
#pragma unroll
        for (int n = 0; n < 2; ++n)
          acc[m][n] = __builtin_amdgcn_mfma_f32_16x16x32_bf16(
              af[m][kk], bg[n][kk], acc[m][n], 0, 0, 0);
  };

  __syncthreads();  // scl visible
  stageB(0, 0);
  buildA(0, 0);
  __syncthreads();  // drains vmcnt (B staged) + lgkm (A written)
  int cur = 0;
  for (int kt = 0; kt < NT - 1; ++kt) {
    stageB(cur ^ 1, kt + 1);   // prefetch next B (in flight across compute)
    buildA(cur ^ 1, kt + 1);   // build next A (VALU overlaps MFMA cross-wave)
    compute(cur);
    __syncthreads();
    cur ^= 1;
  }
  compute(cur);

  // epilogue: C/D layout col=lane&15, row=(lane>>4)*4+reg  [m89/m91]
#pragma unroll
  for (int m = 0; m < 2; ++m)
#pragma unroll
    for (int n = 0; n < 2; ++n) {
      const int col = c0 + wn * 32 + n * 16 + fr;
      const float bc = bias[col];
#pragma unroll
      for (int r = 0; r < 4; ++r) {
        const int row = r0 + wm * 32 + m * 16 + fk * 4 + r;
        out[(size_t)row * O_SZ + col] = acc[m][n][r] + bc;
      }
    }
}

extern "C" void kernel_launch(void* const* d_in, const int* in_sizes, int n_in,
                              void* d_out, int out_size, void* d_ws, size_t ws_size,
                              hipStream_t stream) {
  const float* x     = (const float*)d_in[0];
  const float* bw    = (const float*)d_in[1];
  const float* sw    = (const float*)d_in[2];
  const float* coeff = (const float*)d_in[3];
  const float* bias  = (const float*)d_in[4];
  float* out = (float*)d_out;

  char* ws = (char*)d_ws;
  __hip_bfloat16* Wbuf = (__hip_bfloat16*)ws;                    // 1 MiB
  float* pmin   = (float*)(ws + (size_t)O_SZ * KDIM * 2);        // 128 KiB
  float* pmax   = pmin + 128 * I_SZ;                             // 128 KiB
  float* cenrhw = pmax + 128 * I_SZ;                             // 2 KiB

  minmax_partial<<<128, 256, 0, stream>>>(x, pmin, pmax);
  pack_W<<<(O_SZ * I_SZ) / 256, 256, 0, stream>>>(bw, sw, coeff, Wbuf,
                                                  pmin, pmax, cenrhw);
  gemm_fused<<<(B_SZ / BM) * (O_SZ / BN), 512, 0, stream>>>(x, Wbuf, cenrhw,
                                                            bias, out);
}

// Round 4
// 47.267 us; speedup vs baseline: 1.8037x; 1.1154x over previous
//
#include <hip/hip_runtime.h>
#include <hip/hip_bf16.h>

// Problem constants (KANLayer): B=8192, I=256, O=256, NUM_BASIS=7, ORDER=3
#define B_SZ 8192
#define I_SZ 256
#define O_SZ 256
#define KDIM 2048  // I_SZ * 8  (7 basis + 1 silu per input feature)
#define BM 32      // rows per block
#define BN 128     // output cols per block
#define BKT 64     // K per tile = 8 features
#define NT 32      // KDIM / BKT

typedef __bf16 bf16x8 __attribute__((ext_vector_type(8)));
typedef float f32x4 __attribute__((ext_vector_type(4)));

// Kernel 1: per-column min/max partials. 128 blocks x 256 threads; block
// handles 64 rows via float4 loads (ILP), LDS-reduce over 4 row-subgroups,
// plain stores of one partial row per block (no atomics, no memset needed).
__global__ __launch_bounds__(256) void minmax_partial(
    const float* __restrict__ x, float* __restrict__ pmin,
    float* __restrict__ pmax) {
  const int cg = threadIdx.x & 63;  // column group (4 cols via float4)
  const int rs = threadIdx.x >> 6;  // row subgroup 0..3
  const int r0 = blockIdx.x * 64;
  const float* p = x + (size_t)(r0 + rs) * I_SZ + cg * 4;
  float4 mn = {1e30f, 1e30f, 1e30f, 1e30f};
  float4 mx = {-1e30f, -1e30f, -1e30f, -1e30f};
#pragma unroll
  for (int k = 0; k < 16; ++k) {
    const float4 v = *reinterpret_cast<const float4*>(p + (size_t)k * 4 * I_SZ);
    mn.x = fminf(mn.x, v.x); mn.y = fminf(mn.y, v.y);
    mn.z = fminf(mn.z, v.z); mn.w = fminf(mn.w, v.w);
    mx.x = fmaxf(mx.x, v.x); mx.y = fmaxf(mx.y, v.y);
    mx.z = fmaxf(mx.z, v.z); mx.w = fmaxf(mx.w, v.w);
  }
  __shared__ float rmn[4][I_SZ], rmx[4][I_SZ];
  *reinterpret_cast<float4*>(&rmn[rs][cg * 4]) = mn;
  *reinterpret_cast<float4*>(&rmx[rs][cg * 4]) = mx;
  __syncthreads();
  if (threadIdx.x < 64) {
    float4 a, b;
    const int c0 = threadIdx.x * 4;
    a.x = fminf(fminf(rmn[0][c0+0], rmn[1][c0+0]), fminf(rmn[2][c0+0], rmn[3][c0+0]));
    a.y = fminf(fminf(rmn[0][c0+1], rmn[1][c0+1]), fminf(rmn[2][c0+1], rmn[3][c0+1]));
    a.z = fminf(fminf(rmn[0][c0+2], rmn[1][c0+2]), fminf(rmn[2][c0+2], rmn[3][c0+2]));
    a.w = fminf(fminf(rmn[0][c0+3], rmn[1][c0+3]), fminf(rmn[2][c0+3], rmn[3][c0+3]));
    b.x = fmaxf(fmaxf(rmx[0][c0+0], rmx[1][c0+0]), fmaxf(rmx[2][c0+0], rmx[3][c0+0]));
    b.y = fmaxf(fmaxf(rmx[0][c0+1], rmx[1][c0+1]), fmaxf(rmx[2][c0+1], rmx[3][c0+1]));
    b.z = fmaxf(fmaxf(rmx[0][c0+2], rmx[1][c0+2]), fmaxf(rmx[2][c0+2], rmx[3][c0+2]));
    b.w = fmaxf(fmaxf(rmx[0][c0+3], rmx[1][c0+3]), fmaxf(rmx[2][c0+3], rmx[3][c0+3]));
    *reinterpret_cast<float4*>(&pmin[blockIdx.x * I_SZ + c0]) = a;
    *reinterpret_cast<float4*>(&pmax[blockIdx.x * I_SZ + c0]) = b;
  }
}

// Kernel 2: pack weights -> Wp[o, i*8+m] bf16, pre-swizzled (unit ^= o&7),
// PLUS (block 0) reduce the min/max partials into per-column centre and
// 1/half-width so the GEMM reads scales directly.
__global__ void pack_W(const float* __restrict__ bw,
                       const float* __restrict__ sw,
                       const float* __restrict__ coeff,
                       __hip_bfloat16* __restrict__ W,
                       const float* __restrict__ pmin,
                       const float* __restrict__ pmax,
                       float* __restrict__ cenrhw) {
  const int idx = blockIdx.x * blockDim.x + threadIdx.x;  // 0..O*I-1
  const int i = idx & (I_SZ - 1);
  const int o = idx >> 8;
  const float s = sw[idx];
  union { __hip_bfloat16 h[8]; float4 f4; } u;
#pragma unroll
  for (int m = 0; m < 7; ++m)
    u.h[m] = __float2bfloat16(coeff[(size_t)idx * 7 + m] * s);
  u.h[7] = __float2bfloat16(bw[idx]);
  const size_t off = (size_t)o * KDIM + (size_t)((i ^ (o & 7)) << 3);
  *reinterpret_cast<float4*>(&W[off]) = u.f4;

  if (blockIdx.x == 0) {
    const int c = threadIdx.x;
    float mn = 1e30f, mx = -1e30f;
#pragma unroll 8
    for (int p = 0; p < 128; ++p) {
      mn = fminf(mn, pmin[p * I_SZ + c]);
      mx = fmaxf(mx, pmax[p * I_SZ + c]);
    }
    const float width = fmaxf(mx - mn, 0.01f);
    cenrhw[2 * c]     = 0.5f * (mx + mn);
    cenrhw[2 * c + 1] = 2.0f / width;   // 1/(0.5*width)
  }
}

// ---- async global->LDS 16B copy ----
__device__ __forceinline__ void async16(const __hip_bfloat16* g, __hip_bfloat16* l) {
  __builtin_amdgcn_global_load_lds(
      (const __attribute__((address_space(1))) void*)g,
      (__attribute__((address_space(3))) void*)l, 16, 0, 0);
}

// Kernel 3: fused basis-build + GEMM.
// out[M=8192, N=256] = A(x)[M, K=2048] @ W[N, K]^T + bias, A built on the fly.
// Block = 32 rows x 128 cols, 256 threads (4 waves, 1m x 4n) -> grid 512
// = 2 blocks/CU (cross-block overlap hides barrier stalls). x register-
// prefetched 2 tiles ahead so global latency is off the barrier chain.
__global__ __launch_bounds__(256, 2) void gemm_fused(
    const float* __restrict__ x, const __hip_bfloat16* __restrict__ W,
    const float* __restrict__ cenrhw, const float* __restrict__ bias,
    float* __restrict__ out) {
  __shared__ __align__(16) __hip_bfloat16 Alds[2][BM * BKT];   // 2 x 4KB
  __shared__ __align__(16) __hip_bfloat16 Blds[2][BN * BKT];   // 2 x 16KB
  __shared__ float2 scl[I_SZ];                                  // 2KB

  const int t = threadIdx.x;
  const int lane = t & 63;
  const int wave = t >> 6;            // 0..3 -> n-offset 32*wave
  const int fr = lane & 15, fk = lane >> 4;

  // XCD-aware bijective swizzle (512 blocks, %8==0); (bn=0,1) of the same bm
  // land adjacent on one XCD -> shared x rows / W panels hit L2.
  const int bid = blockIdx.x;
  const int swz = (bid & 7) * 64 + (bid >> 3);
  const int bm = swz >> 1, bn = swz & 1;
  const int r0 = bm * BM;    // batch-row base
  const int c0 = bn * BN;    // output-col base

  // per-column scale factors -> LDS
  scl[t] = reinterpret_cast<const float2*>(cenrhw)[t];

  // A-build mapping: thread -> (row, feature-within-tile); one eval/thread
  const int arow = t >> 3;   // 0..31
  const int af_  = t & 7;    // 0..7
  const float* xp = x + (size_t)(r0 + arow) * I_SZ + af_;

  // B staging: 1024 16B-units; thread t covers units {t, 256+t, 512+t, 768+t}
  const __hip_bfloat16* gb0 = W + (size_t)(c0 + (t >> 3)) * KDIM + (t & 7) * 8;

  f32x4 acc[2][2] = {{{0.f,0.f,0.f,0.f},{0.f,0.f,0.f,0.f}},
                     {{0.f,0.f,0.f,0.f},{0.f,0.f,0.f,0.f}}};

  auto stageB = [&](int buf, int kt) {
    const size_t k0 = (size_t)kt * BKT;
    async16(gb0 + k0,                      &Blds[buf][t * 8]);
    async16(gb0 + k0 + (size_t)32 * KDIM,  &Blds[buf][2048 + t * 8]);
    async16(gb0 + k0 + (size_t)64 * KDIM,  &Blds[buf][4096 + t * 8]);
    async16(gb0 + k0 + (size_t)96 * KDIM,  &Blds[buf][6144 + t * 8]);
  };

  auto buildA = [&](int buf, int kt, float xv) {
    const int i = kt * 8 + af_;
    const float2 s = scl[i];
    float xn = (xv - s.x) * s.y;
    xn = fminf(fmaxf(xn, -2.0f), 2.0f);
    // d[j] = xn - KT[j], KT[j] = -1 + 0.2j (uniform knots)
    float d[11];
#pragma unroll
    for (int j = 0; j < 11; ++j) d[j] = xn - (-1.0f + 0.2f * j);
    float bas[7];
#pragma unroll
    for (int j = 0; j < 7; ++j)
      bas[j] = (d[j] >= 0.0f && d[j + 1] < 0.0f) ? 1.0f : 0.0f;
    if (d[7] == 0.0f) bas[6] = 1.0f;  // xe == KNOTS[7] special case
    // truncated de Boor; uniform knots: both denominators = 0.2k
#pragma unroll
    for (int k = 1; k <= 3; ++k) {
      const float rk = (k == 1) ? 5.0f : (k == 2) ? 2.5f : (1.0f / 0.6f);
#pragma unroll
      for (int j = 0; j < 7; ++j) {
        const float bn_ = (j < 6) ? bas[j + 1] : 0.0f;
        bas[j] = (d[j] * bas[j] - d[j + k + 1] * bn_) * rk;
      }
    }
    const float silu = xn / (1.0f + __expf(-xn));
    union { __hip_bfloat16 h[8]; float4 f4; } u;
#pragma unroll
    for (int m = 0; m < 7; ++m) u.h[m] = __float2bfloat16(bas[m]);
    u.h[7] = __float2bfloat16(silu);
    const int unit = af_ ^ (arow & 7);
    *reinterpret_cast<float4*>(&Alds[buf][arow * BKT + unit * 8]) = u.f4;
  };

  auto compute = [&](int buf) {
    bf16x8 af[2][2], bg[2][2];
#pragma unroll
    for (int m = 0; m < 2; ++m)
#pragma unroll
      for (int kk = 0; kk < 2; ++kk) {
        const int row = m * 16 + fr;
        const int unit = ((kk << 2) | fk) ^ (row & 7);
        af[m][kk] = *reinterpret_cast<const bf16x8*>(&Alds[buf][row * BKT + unit * 8]);
      }
#pragma unroll
    for (int n = 0; n < 2; ++n)
#pragma unroll
      for (int kk = 0; kk < 2; ++kk) {
        const int row = wave * 32 + n * 16 + fr;
        const int unit = ((kk << 2) | fk) ^ (row & 7);
        bg[n][kk] = *reinterpret_cast<const bf16x8*>(&Blds[buf][row * BKT + unit * 8]);
      }
#pragma unroll
    for (int kk = 0; kk < 2; ++kk)
#pragma unroll
      for (int m = 0; m < 2; ++m)
#pragma unroll
        for (int n = 0; n < 2; ++n)
          acc[m][n] = __builtin_amdgcn_mfma_f32_16x16x32_bf16(
              af[m][kk], bg[n][kk], acc[m][n], 0, 0, 0);
  };

  // prologue: x for tile 0 (used now) and tile 1 (used next) in flight early
  const float xv0 = xp[0];
  float xpf = xp[8];            // tile 1
  __syncthreads();              // scl visible
  stageB(0, 0);
  buildA(0, 0, xv0);
  __syncthreads();              // A written + B staged (vmcnt+lgkm drained)
  int cur = 0;
  for (int kt = 0; kt < NT - 1; ++kt) {
    stageB(cur ^ 1, kt + 1);
    float xpf2 = (kt + 2 < NT) ? xp[(kt + 2) * 8] : 0.0f;  // issue early
    buildA(cur ^ 1, kt + 1, xpf);   // consumes value prefetched last iter
    compute(cur);
    __syncthreads();
    xpf = xpf2;
    cur ^= 1;
  }
  compute(cur);

  // epilogue: C/D layout col=lane&15, row=(lane>>4)*4+reg  [m89/m91]
#pragma unroll
  for (int m = 0; m < 2; ++m)
#pragma unroll
    for (int n = 0; n < 2; ++n) {
      const int col = c0 + wave * 32 + n * 16 + fr;
      const float bc = bias[col];
#pragma unroll
      for (int r = 0; r < 4; ++r) {
        const int row = r0 + m * 16 + fk * 4 + r;
        out[(size_t)row * O_SZ + col] = acc[m][n][r] + bc;
      }
    }
}

extern "C" void kernel_launch(void* const* d_in, const int* in_sizes, int n_in,
                              void* d_out, int out_size, void* d_ws, size_t ws_size,
                              hipStream_t stream) {
  const float* x     = (const float*)d_in[0];
  const float* bw    = (const float*)d_in[1];
  const float* sw    = (const float*)d_in[2];
  const float* coeff = (const float*)d_in[3];
  const float* bias  = (const float*)d_in[4];
  float* out = (float*)d_out;

  char* ws = (char*)d_ws;
  __hip_bfloat16* Wbuf = (__hip_bfloat16*)ws;                    // 1 MiB
  float* pmin   = (float*)(ws + (size_t)O_SZ * KDIM * 2);        // 128 KiB
  float* pmax   = pmin + 128 * I_SZ;                             // 128 KiB
  float* cenrhw = pmax + 128 * I_SZ;                             // 2 KiB

  minmax_partial<<<128, 256, 0, stream>>>(x, pmin, pmax);
  pack_W<<<(O_SZ * I_SZ) / 256, 256, 0, stream>>>(bw, sw, coeff, Wbuf,
                                                  pmin, pmax, cenrhw);
  gemm_fused<<<(B_SZ / BM) * (O_SZ / BN), 256, 0, stream>>>(x, Wbuf, cenrhw,
                                                            bias, out);
}